// Round 3
// baseline (50.286 us; speedup 1.0000x reference)
//
#include <hip/hip_runtime.h>
#include <math.h>

#ifndef M_PI
#define M_PI 3.14159265358979323846
#endif

// sin(3e-4 * pi/10): same effective boundary margin as the passing round-2
// kernel (|p - rint(p)| * min(mag,1) < 3e-4), expressed in m_k space.
#define THR_BASE 9.42477e-5f

// x: (16,1,512,512) f32 ; out: (16,10,64,64) f32
// thread t -> (n, ch, cw, r): r = t & 7 (pixel row within 8x8 cell)
// 8 lanes (one cell) share 10 LDS bins via ds_add_f32.
__global__ void __launch_bounds__(256) hog_kernel(const float* __restrict__ x,
                                                  float* __restrict__ out) {
    __shared__ float sbins[32 * 11];  // 32 cells/block, stride 11 (bank spread)

    int tid = threadIdx.x;
    for (int i = tid; i < 32 * 11; i += 256) sbins[i] = 0.0f;
    __syncthreads();

    int t    = blockIdx.x * 256 + tid;
    int r    = t & 7;
    int cell = t >> 3;           // 0 .. 65535
    int cw   = cell & 63;
    int ch   = (cell >> 6) & 63;
    int n    = cell >> 12;
    float* mybins = &sbins[(tid >> 3) * 11];

    const float* img = x + (size_t)n * (512 * 512);
    int row  = ch * 8 + r;       // pixel row this thread handles
    int col0 = cw * 8;           // first pixel column of the cell

    // Halo load: 3 rows x 10 cols, zero-padded. Two aligned float4 + 2 edges.
    float xr[3][10];
#pragma unroll
    for (int dr = 0; dr < 3; ++dr) {
        int rr = row + dr - 1;
        bool rok = (rr >= 0) && (rr < 512);
        const float* rp = img + (size_t)(rok ? rr : row) * 512;  // safe addr
        const float4* rp4 = (const float4*)(rp + col0);          // 16B aligned
        float4 v0 = rp4[0];
        float4 v1 = rp4[1];
        float lf = rp[(cw > 0) ? (col0 - 1) : col0];
        float rt = rp[(cw < 63) ? (col0 + 8) : col0];
        lf = (cw > 0 && rok) ? lf : 0.0f;
        rt = (cw < 63 && rok) ? rt : 0.0f;
        float m = rok ? 1.0f : 0.0f;  // zero out-of-range rows
        xr[dr][0] = lf;
        xr[dr][1] = v0.x * m; xr[dr][2] = v0.y * m;
        xr[dr][3] = v0.z * m; xr[dr][4] = v0.w * m;
        xr[dr][5] = v1.x * m; xr[dr][6] = v1.y * m;
        xr[dr][7] = v1.z * m; xr[dr][8] = v1.w * m;
        xr[dr][9] = rt;
    }

#pragma unroll
    for (int c = 0; c < 8; ++c) {
        float a0 = xr[0][c], a1 = xr[0][c + 1], a2 = xr[0][c + 2];
        float b0 = xr[1][c],                    b2 = xr[1][c + 2];
        float c0 = xr[2][c], c1 = xr[2][c + 1], c2 = xr[2][c + 2];

        // Same association order as the passing round-2 kernel.
        float gx = ((((a0 - a2) + 2.0f * b0) - 2.0f * b2) + c0) - c2;
        float gy = ((((a0 + 2.0f * a1) + a2) - c0) - 2.0f * c1) - c2;

        float mag = sqrtf(gx * gx + gy * gy);
        float a = fabsf(gx), b = fabsf(gy);

        // Sector tests: m_k = a*cos(k*pi/10) - b*sin(k*pi/10), k=1..4
        float m1 = fmaf(a, 0.95105651629515353f, -(b * 0.30901699437494740f));
        float m2 = fmaf(a, 0.80901699437494745f, -(b * 0.58778525229247314f));
        float m3 = fmaf(a, 0.58778525229247314f, -(b * 0.80901699437494745f));
        float m4 = fmaf(a, 0.30901699437494740f, -(b * 0.95105651629515353f));
        int s = (m1 >= 0.0f) + (m2 >= 0.0f) + (m3 >= 0.0f) + (m4 >= 0.0f);
        int q = (int)((__float_as_uint(gx) ^ __float_as_uint(gy)) >> 31);
        int fl = q ? (9 - s) : s;
        int ce = (fl == 9) ? 0 : (fl + 1);

        // Distance to nearest bin boundary (in mag*sin(angle) units)
        float dmin = fminf(fminf(fminf(fabsf(m1), fabsf(m2)),
                                 fminf(fabsf(m3), fabsf(m4))),
                           fminf(a, b));

        if (dmin < THR_BASE * fmaxf(mag, 1.0f)) {
            // Boundary-accurate path: exact conv in double + double atan2.
            double gxd = ((((((double)a0 - (double)a2) + 2.0 * (double)b0)
                            - 2.0 * (double)b2) + (double)c0) - (double)c2);
            double gyd = ((((((double)a0 + 2.0 * (double)a1) + (double)a2)
                            - (double)c0) - 2.0 * (double)c1) - (double)c2);
            if (gxd == 0.0) {                 // p = 0 / +-10 -> bin 0
                fl = 0; ce = 0;
            } else if (gyd == 0.0) {          // p = +-5 exactly -> bin 5
                fl = 5; ce = 5;
            } else {
                double pt = atan2(gxd, gyd) * (10.0 / M_PI);
                int fli = (int)floor(pt);
                int cei = (int)ceil(pt);
                fl = ((fli % 10) + 10) % 10;
                ce = ((cei % 10) + 10) % 10;
            }
        }

        float om = 1.0f - mag;
        atomicAdd(&mybins[fl], mag);
        atomicAdd(&mybins[ce], om);
    }

    // 8 lanes of this cell are in the same wave: their ds_add ops complete
    // in order before the reads below (no barrier needed).
    float* opb = out + (((size_t)n * 10) * 64 + ch) * 64 + cw;
    opb[(size_t)r * 4096] = mybins[r] * (1.0f / 64.0f);
    if (r < 2) {
        opb[(size_t)(8 + r) * 4096] = mybins[8 + r] * (1.0f / 64.0f);
    }
}

extern "C" void kernel_launch(void* const* d_in, const int* in_sizes, int n_in,
                              void* d_out, int out_size, void* d_ws, size_t ws_size,
                              hipStream_t stream) {
    const float* x = (const float*)d_in[0];
    float* out = (float*)d_out;
    const int total = 16 * 64 * 64 * 8;  // 524288 threads
    hog_kernel<<<total / 256, 256, 0, stream>>>(x, out);
}

// Round 4
// 20.837 us; speedup vs baseline: 2.4133x; 2.4133x over previous
//
#include <hip/hip_runtime.h>
#include <math.h>

#ifndef M_PI
#define M_PI 3.14159265358979323846
#endif

// sin(3e-4 * pi/10): boundary margin in m_k units, same effective margin as
// the passing round-2/3 kernels; ~100x the worst fp32 conv/sector error.
#define THR_BASE 9.42477e-5f

// x: (16,1,512,512) f32 ; out: (16,10,64,64) f32
// thread t -> (n, ch, cw, r): r = t & 7 (pixel row within 8x8 cell)
// Register bins + 8-lane shuffle reduce. No LDS, no atomics.
__global__ void __launch_bounds__(256) hog_kernel(const float* __restrict__ x,
                                                  float* __restrict__ out) {
    int t    = blockIdx.x * 256 + threadIdx.x;
    int r    = t & 7;
    int cell = t >> 3;           // 0 .. 65535
    int cw   = cell & 63;
    int ch   = (cell >> 6) & 63;
    int n    = cell >> 12;

    const float* img = x + (size_t)n * (512 * 512);
    int row  = ch * 8 + r;       // pixel row this thread handles
    int col0 = cw * 8;           // first pixel column of the cell

    // Halo load: 3 rows x 10 cols, zero-padded. Two aligned float4 + 2 edges.
    float xr[3][10];
#pragma unroll
    for (int dr = 0; dr < 3; ++dr) {
        int rr = row + dr - 1;
        bool rok = (rr >= 0) && (rr < 512);
        const float* rp = img + (size_t)(rok ? rr : row) * 512;  // safe addr
        const float4* rp4 = (const float4*)(rp + col0);          // 32B aligned
        float4 v0 = rp4[0];
        float4 v1 = rp4[1];
        float lf = rp[(cw > 0) ? (col0 - 1) : col0];
        float rt = rp[(cw < 63) ? (col0 + 8) : col0];
        lf = (cw > 0 && rok) ? lf : 0.0f;
        rt = (cw < 63 && rok) ? rt : 0.0f;
        float m = rok ? 1.0f : 0.0f;  // zero out-of-range rows
        xr[dr][0] = lf;
        xr[dr][1] = v0.x * m; xr[dr][2] = v0.y * m;
        xr[dr][3] = v0.z * m; xr[dr][4] = v0.w * m;
        xr[dr][5] = v1.x * m; xr[dr][6] = v1.y * m;
        xr[dr][7] = v1.z * m; xr[dr][8] = v1.w * m;
        xr[dr][9] = rt;
    }

    // Column sums for gx: d[c] = x0[c] + 2*x1[c] + x2[c]; gx = d[c]-d[c+2].
    float d[10];
#pragma unroll
    for (int c = 0; c < 10; ++c)
        d[c] = fmaf(2.0f, xr[1][c], xr[0][c] + xr[2][c]);

    float cmagF[10], sacc[10];
#pragma unroll
    for (int b = 0; b < 10; ++b) { cmagF[b] = 0.0f; sacc[b] = 0.0f; }
    unsigned long long pk = 0ull;   // 10 x 4-bit per-bin pixel counts (<=8)

#pragma unroll
    for (int c = 0; c < 8; ++c) {
        float a0 = xr[0][c], a1 = xr[0][c + 1], a2 = xr[0][c + 2];
        float c0 = xr[2][c], c1 = xr[2][c + 1], c2 = xr[2][c + 2];

        float gx = d[c] - d[c + 2];
        float gy = (a0 + 2.0f * a1 + a2) - (c0 + 2.0f * c1 + c2);

        float mag = sqrtf(gx * gx + gy * gy);
        float a = fabsf(gx), b = fabsf(gy);

        // Sector tests: m_k = a*cos(k*pi/10) - b*sin(k*pi/10), k=1..4
        float m1 = fmaf(a, 0.95105651629515353f, -(b * 0.30901699437494740f));
        float m2 = fmaf(a, 0.80901699437494745f, -(b * 0.58778525229247314f));
        float m3 = fmaf(a, 0.58778525229247314f, -(b * 0.80901699437494745f));
        float m4 = fmaf(a, 0.30901699437494740f, -(b * 0.95105651629515353f));
        int s = (int)(m1 >= 0.0f) + (int)(m2 >= 0.0f) +
                (int)(m3 >= 0.0f) + (int)(m4 >= 0.0f);
        int q = (int)((__float_as_uint(gx) ^ __float_as_uint(gy)) >> 31);
        int fl = q ? (9 - s) : s;

        // Distance to nearest bin boundary (in mag-scaled units)
        float dmin = fminf(fminf(fminf(fabsf(m1), fabsf(m2)),
                                 fminf(fabsf(m3), fabsf(m4))),
                           fminf(a, b));

        if (dmin >= THR_BASE * fmaxf(mag, 1.0f)) {
            // Fast path: ce = fl+1 (mod 10) guaranteed; om handled via count.
#pragma unroll
            for (int bb = 0; bb < 10; ++bb)
                cmagF[bb] += (bb == fl) ? mag : 0.0f;
            pk += 1ull << (fl * 4);
        } else {
            // Boundary-accurate path: exact conv in double + double atan2.
            float b0 = xr[1][c], b2 = xr[1][c + 2];
            double gxd = ((((((double)a0 - (double)a2) + 2.0 * (double)b0)
                            - 2.0 * (double)b2) + (double)c0) - (double)c2);
            double gyd = ((((((double)a0 + 2.0 * (double)a1) + (double)a2)
                            - (double)c0) - 2.0 * (double)c1) - (double)c2);
            int fle, cee;
            if (gxd == 0.0) {                 // p = 0 / +-10 -> bin 0
                fle = 0; cee = 0;
            } else if (gyd == 0.0) {          // p = +-5 exactly -> bin 5
                fle = 5; cee = 5;
            } else {
                double pt = atan2(gxd, gyd) * (10.0 / M_PI);
                int fli = (int)floor(pt);
                int cei = (int)ceil(pt);
                fle = ((fli % 10) + 10) % 10;
                cee = ((cei % 10) + 10) % 10;
            }
            float om = 1.0f - mag;
#pragma unroll
            for (int bb = 0; bb < 10; ++bb)
                sacc[bb] += ((bb == fle) ? mag : 0.0f) +
                            ((bb == cee) ? om  : 0.0f);
        }
    }

    // Per-thread bins: bins[b] = cmagF[b] + sum_{ce==b}(1-mag) + slow-path adds
    //                = cmagF[b] + cnt[b-1] - cmagF[b-1] + sacc[b]
    float bins[10];
#pragma unroll
    for (int b = 0; b < 10; ++b) {
        int bm1 = (b + 9) % 10;
        float cnt = (float)(unsigned)((pk >> (bm1 * 4)) & 15ull);
        bins[b] = (cmagF[b] - cmagF[bm1]) + cnt + sacc[b];
    }

    // Reduce the 8 row-threads of each cell (lanes r=0..7 contiguous)
#pragma unroll
    for (int b = 0; b < 10; ++b) {
        float v = bins[b];
        v += __shfl_xor(v, 1);
        v += __shfl_xor(v, 2);
        v += __shfl_xor(v, 4);
        bins[b] = v;
    }

    if (r == 0) {
        float* op = out + (((size_t)n * 10) * 64 + ch) * 64 + cw;
#pragma unroll
        for (int b = 0; b < 10; ++b)
            op[(size_t)b * 4096] = bins[b] * (1.0f / 64.0f);
    }
}

extern "C" void kernel_launch(void* const* d_in, const int* in_sizes, int n_in,
                              void* d_out, int out_size, void* d_ws, size_t ws_size,
                              hipStream_t stream) {
    const float* x = (const float*)d_in[0];
    float* out = (float*)d_out;
    const int total = 16 * 64 * 64 * 8;  // 524288 threads
    hog_kernel<<<total / 256, 256, 0, stream>>>(x, out);
}